// Round 8
// baseline (581.783 us; speedup 1.0000x reference)
//
#include <hip/hip_runtime.h>
#include <hip/hip_bf16.h>
#include <stdint.h>

typedef unsigned short u16;
typedef __bf16 bf16x8 __attribute__((ext_vector_type(8)));
typedef float  f32x4  __attribute__((ext_vector_type(4)));
typedef u16    u16x8  __attribute__((ext_vector_type(8)));

__device__ __forceinline__ float bf2f(u16 u) {
    return __uint_as_float(((unsigned)u) << 16);
}
__device__ __forceinline__ u16 f2bf(float f) {   // round-to-nearest-even
    unsigned u = __float_as_uint(f);
    u += 0x7fffu + ((u >> 16) & 1u);
    return (u16)(u >> 16);
}
__device__ __forceinline__ u16x8 maxu16(u16x8 a, u16x8 b) {
    u16x8 r;
    #pragma unroll
    for (int e = 0; e < 8; ++e) r[e] = a[e] > b[e] ? a[e] : b[e];
    return r;
}
__device__ __forceinline__ u16x8 shfl_xor16(u16x8 v, int mask) {
    union { u16x8 u; int i[4]; } a, r;
    a.u = v;
    #pragma unroll
    for (int t = 0; t < 4; ++t) r.i[t] = __shfl_xor(a.i[t], mask, 64);
    return r.u;
}

#define MFMA16(a, b, c) __builtin_amdgcn_mfma_f32_16x16x32_bf16(a, b, c, 0, 0, 0)

// Static device buffers — no d_ws dependency.
__device__ u16   h2g_buf[262144 * 64];   // h2 [N][64] bf16 (33.5 MB)
__device__ u16   gm_buf [262144 * 64];   // neighbor-max [N][64] bf16 (33.5 MB)
__device__ u16   w3b[64 * 64];           // weights pre-converted to bf16
__device__ u16   w4b[128 * 64];
__device__ u16   w5b[1024 * 192];
__device__ float g_buf[1024];            // global column max (>= 0)
__device__ float f1_buf[512];
__device__ float f2_buf[256];

// ---------------------------------------------------------------------------
__global__ void k0_zero() { g_buf[threadIdx.x] = 0.f; }

__global__ void kcvt(const float* __restrict__ w3f, const float* __restrict__ w4f,
                     const float* __restrict__ w5f)
{
    int i = blockIdx.x * 256 + threadIdx.x;
    if (i < 4096)        w3b[i]         = f2bf(w3f[i]);
    else if (i < 12288)  w4b[i - 4096]  = f2bf(w4f[i - 4096]);
    else                 w5b[i - 12288] = f2bf(w5f[i - 12288]);
}

// ---------------------------------------------------------------------------
// k1: mlp1+mlp2 for 64 points/block (f32 in -> bf16). Writes h2g_buf.
// ---------------------------------------------------------------------------
__global__ __launch_bounds__(256) void k1_mlp(
    const float* __restrict__ xf, const float* __restrict__ w1f,
    const float* __restrict__ w2f)
{
    __shared__ __align__(16) u16 sw1[64 * 4];
    __shared__ __align__(16) u16 sx [64 * 4];
    __shared__ __align__(16) u16 sw2[64 * 72];
    __shared__ __align__(16) u16 shA[64 * 72];
    __shared__ __align__(16) u16 sh2[64 * 72];

    const int tid = threadIdx.x;
    const int p0  = blockIdx.x * 64;

    for (int i = tid; i < 64 * 64; i += 256)
        sw2[(i >> 6) * 72 + (i & 63)] = f2bf(w2f[i]);
    if (tid < 192) {
        sw1[(tid / 3) * 4 + tid % 3] = f2bf(w1f[tid]);
        sx [(tid / 3) * 4 + tid % 3] = f2bf(xf[p0 * 3 + tid]);
    }
    __syncthreads();

    {   // L1 via VALU (K=3)
        int m = tid & 63, ng = tid >> 6;
        float x0 = bf2f(sx[m * 4]), x1 = bf2f(sx[m * 4 + 1]), x2 = bf2f(sx[m * 4 + 2]);
        #pragma unroll
        for (int j = 0; j < 16; ++j) {
            int n = ng * 16 + j;
            float s = x0 * bf2f(sw1[n * 4]) + x1 * bf2f(sw1[n * 4 + 1]) + x2 * bf2f(sw1[n * 4 + 2]);
            shA[m * 72 + n] = f2bf(fmaxf(s, 0.f));
        }
    }
    __syncthreads();

    const int lane = tid & 63, w = tid >> 6, q = lane >> 4, l15 = lane & 15;
    const int mrow = 16 * w;

    f32x4 acc2[4];
    #pragma unroll
    for (int nt = 0; nt < 4; ++nt) acc2[nt] = (f32x4){0.f, 0.f, 0.f, 0.f};
    #pragma unroll
    for (int s = 0; s < 2; ++s) {
        bf16x8 a = *(const bf16x8*)&shA[(mrow + l15) * 72 + s * 32 + q * 8];
        #pragma unroll
        for (int nt = 0; nt < 4; ++nt) {
            bf16x8 b = *(const bf16x8*)&sw2[(nt * 16 + l15) * 72 + s * 32 + q * 8];
            acc2[nt] = MFMA16(a, b, acc2[nt]);
        }
    }
    #pragma unroll
    for (int nt = 0; nt < 4; ++nt)
        #pragma unroll
        for (int r = 0; r < 4; ++r) {
            int m = mrow + q * 4 + r;
            sh2[m * 72 + nt * 16 + l15] = f2bf(fmaxf(acc2[nt][r], 0.f));
        }
    __syncthreads();

    {
        int row = tid >> 2, c = (tid & 3) * 16;
        *(u16x8*)&h2g_buf[(size_t)p0 * 64 + tid * 16]     = *(const u16x8*)&sh2[row * 72 + c];
        *(u16x8*)&h2g_buf[(size_t)p0 * 64 + tid * 16 + 8] = *(const u16x8*)&sh2[row * 72 + c + 8];
    }
}

// ---------------------------------------------------------------------------
// k2_pool: one wave per 4 points -> 8 x 1KB gathers in flight (4x the MLP of
//   round 7). Packed-u16 max (valid: post-relu bf16 >= 0), xor-shuffle reduce.
// ---------------------------------------------------------------------------
__global__ __launch_bounds__(256) void k2_pool(const int* __restrict__ idx)
{
    const int wv   = threadIdx.x >> 6;
    const size_t p0 = ((size_t)blockIdx.x * 4 + wv) * 4;   // 4 points per wave
    const int lane = threadIdx.x & 63;
    const int k = lane >> 3, c = lane & 7;

    int js[8];
    #pragma unroll
    for (int t = 0; t < 4; ++t) {
        js[2 * t]     = idx[(p0 + t) * 16 + k];
        js[2 * t + 1] = idx[(p0 + t) * 16 + 8 + k];
    }
    u16x8 v[8];
    #pragma unroll
    for (int u = 0; u < 8; ++u)
        v[u] = *(const u16x8*)&h2g_buf[(size_t)js[u] * 64 + c * 8];

    u16x8 m[4];
    #pragma unroll
    for (int t = 0; t < 4; ++t) {
        u16x8 mm = maxu16(v[2 * t], v[2 * t + 1]);
        mm = maxu16(mm, shfl_xor16(mm, 8));
        mm = maxu16(mm, shfl_xor16(mm, 16));
        mm = maxu16(mm, shfl_xor16(mm, 32));
        m[t] = mm;
    }
    if (lane < 32) {                    // lane = 8t + c writes point p0+t
        u16x8 out = (k == 0) ? m[0] : (k == 1) ? m[1] : (k == 2) ? m[2] : m[3];
        *(u16x8*)&gm_buf[(p0 + k) * 64 + c * 8] = out;
    }
}

// ---------------------------------------------------------------------------
// k3: per 128-row block, single 48KB LDS tile sA[128][192] (swizzled
//   (r,k) -> r*192 + P*8 + (k&7), P=(j&24)|((j^r)&7), j=k>>3):
//     stage gm -> cols 0..63, h2 -> cols 64..127
//     P4 h3 = relu(h2@w3^T) -> cols 128..191   (wave-local rows, no barrier)
//     P5 h4 = relu(h3@w4^T) -> cols 64..191    (overwrites h2+h3; safe via
//                                               within-wave data deps)
//   Then ALL 24 A-frags cached in VGPRs (sA read exactly once), and the mlp5
//   bn-loop runs with B-frags loaded DIRECTLY from w5b (L2-resident, 384KB)
//   with one-step prefetch: zero LDS traffic, zero barriers in the hot loop.
// ---------------------------------------------------------------------------
__global__ __launch_bounds__(256) void k3_fused(int* __restrict__ g)
{
    __shared__ __align__(16) u16 sA[128 * 192];   // 48 KB

    const int tid  = threadIdx.x;
    const size_t R0 = (size_t)blockIdx.x * 128;
    const int lane = tid & 63, w = tid >> 6, q = lane >> 4, l15 = lane & 15;
    const int m0w  = (w & 1) * 64, n0w = (w >> 1) * 64;

    // ---- stage gm -> cols 0..63 (j=0..7), h2 -> cols 64..127 (j=8..15) ----
    #pragma unroll
    for (int c = 0; c < 4; ++c) {
        int i = c * 256 + tid, r = i >> 3, js = i & 7;
        *(u16x8*)&sA[r * 192 + ((js ^ r) & 7) * 8] =
            *(const u16x8*)&gm_buf[(R0 + r) * 64 + js * 8];
        *(u16x8*)&sA[r * 192 + (8 | ((js ^ r) & 7)) * 8] =
            *(const u16x8*)&h2g_buf[(R0 + r) * 64 + js * 8];
    }
    __syncthreads();

    // ---- P4: h3 = relu(h2 @ w3^T) -> cols 128..191 (wave-local rows) ----
    {
        f32x4 a3[2][4];
        #pragma unroll
        for (int mt = 0; mt < 2; ++mt)
            #pragma unroll
            for (int nt = 0; nt < 4; ++nt) a3[mt][nt] = (f32x4){0.f, 0.f, 0.f, 0.f};
        #pragma unroll
        for (int ss = 0; ss < 2; ++ss) {
            int js = ss * 4 + q;
            bf16x8 a[2], b[4];
            #pragma unroll
            for (int mt = 0; mt < 2; ++mt) {
                int r = w * 32 + mt * 16 + l15;
                a[mt] = *(const bf16x8*)&sA[r * 192 + (8 | ((js ^ r) & 7)) * 8];
            }
            #pragma unroll
            for (int nt = 0; nt < 4; ++nt)
                b[nt] = *(const bf16x8*)&w3b[(nt * 16 + l15) * 64 + ss * 32 + q * 8];
            #pragma unroll
            for (int mt = 0; mt < 2; ++mt)
                #pragma unroll
                for (int nt = 0; nt < 4; ++nt)
                    a3[mt][nt] = MFMA16(a[mt], b[nt], a3[mt][nt]);
        }
        #pragma unroll
        for (int mt = 0; mt < 2; ++mt)
            #pragma unroll
            for (int nt = 0; nt < 4; ++nt)
                #pragma unroll
                for (int r = 0; r < 4; ++r) {
                    int m = w * 32 + mt * 16 + q * 4 + r;
                    int n = nt * 16 + l15;
                    sA[m * 192 + (16 | (((n >> 3) ^ m) & 7)) * 8 + (n & 7)] =
                        f2bf(fmaxf(a3[mt][nt][r], 0.f));
                }
    }
    // no barrier: P4 writes and P5 reads are wave-local rows

    // ---- P5: h4 = relu(h3 @ w4^T) -> cols 64..191 ----
    {
        f32x4 a4[2][8];
        #pragma unroll
        for (int mt = 0; mt < 2; ++mt)
            #pragma unroll
            for (int nt = 0; nt < 8; ++nt) a4[mt][nt] = (f32x4){0.f, 0.f, 0.f, 0.f};
        #pragma unroll
        for (int ss = 0; ss < 2; ++ss) {
            int js = ss * 4 + q;
            bf16x8 a[2];
            #pragma unroll
            for (int mt = 0; mt < 2; ++mt) {
                int r = w * 32 + mt * 16 + l15;
                a[mt] = *(const bf16x8*)&sA[r * 192 + (16 | ((js ^ r) & 7)) * 8];
            }
            #pragma unroll
            for (int nt = 0; nt < 8; ++nt) {
                bf16x8 b = *(const bf16x8*)&w4b[(nt * 16 + l15) * 64 + ss * 32 + q * 8];
                #pragma unroll
                for (int mt = 0; mt < 2; ++mt)
                    a4[mt][nt] = MFMA16(a[mt], b, a4[mt][nt]);
            }
        }
        // writes ordered after reads by within-wave data deps (same rows)
        #pragma unroll
        for (int mt = 0; mt < 2; ++mt)
            #pragma unroll
            for (int nt = 0; nt < 8; ++nt)
                #pragma unroll
                for (int r = 0; r < 4; ++r) {
                    int m  = w * 32 + mt * 16 + q * 4 + r;
                    int n4 = nt * 16 + l15;
                    int j  = 8 + (n4 >> 3);
                    int p  = (j & 24) | ((j ^ m) & 7);
                    sA[m * 192 + p * 8 + (n4 & 7)] = f2bf(fmaxf(a4[mt][nt][r], 0.f));
                }
    }
    __syncthreads();

    // ---- cache all 24 A-frags in VGPRs (sA read exactly once) ----
    bf16x8 areg[3][2][4];                 // [kt][ss][mt]
    #pragma unroll
    for (int kt = 0; kt < 3; ++kt)
        #pragma unroll
        for (int ss = 0; ss < 2; ++ss) {
            int js = ss * 4 + q;
            #pragma unroll
            for (int mt = 0; mt < 4; ++mt) {
                int r = m0w + mt * 16 + l15;
                int p = (kt * 8) | ((js ^ r) & 7);
                areg[kt][ss][mt] = *(const bf16x8*)&sA[r * 192 + p * 8];
            }
        }

    // ---- mlp5: B direct from w5b (L2), one-step prefetch, no barriers ----
    const size_t bbase = (size_t)(n0w + l15) * 192 + q * 8;   // + nt*16*192 + bn*128*192 + kt*64 + ss*32
    bf16x8 bc[2][4], bx[2][4];
    #pragma unroll
    for (int ss = 0; ss < 2; ++ss)
        #pragma unroll
        for (int nt = 0; nt < 4; ++nt)
            bc[ss][nt] = *(const bf16x8*)&w5b[bbase + (size_t)nt * 3072 + ss * 32];

    int bn1 = 0, kt1 = 1;                 // coords of next stage
    for (int bn = 0; bn < 8; ++bn) {
        f32x4 acc[4][4];
        #pragma unroll
        for (int mt = 0; mt < 4; ++mt)
            #pragma unroll
            for (int nt = 0; nt < 4; ++nt) acc[mt][nt] = (f32x4){0.f, 0.f, 0.f, 0.f};

        #pragma unroll
        for (int kt = 0; kt < 3; ++kt) {
            if (bn * 3 + kt < 23) {
                size_t nb = bbase + (size_t)bn1 * 24576 + kt1 * 64;
                #pragma unroll
                for (int ss = 0; ss < 2; ++ss)
                    #pragma unroll
                    for (int nt = 0; nt < 4; ++nt)
                        bx[ss][nt] = *(const bf16x8*)&w5b[nb + (size_t)nt * 3072 + ss * 32];
                if (++kt1 == 3) { kt1 = 0; ++bn1; }
            }
            #pragma unroll
            for (int ss = 0; ss < 2; ++ss)
                #pragma unroll
                for (int mt = 0; mt < 4; ++mt)
                    #pragma unroll
                    for (int nt = 0; nt < 4; ++nt)
                        acc[mt][nt] = MFMA16(areg[kt][ss][mt], bc[ss][nt], acc[mt][nt]);
            #pragma unroll
            for (int ss = 0; ss < 2; ++ss)
                #pragma unroll
                for (int nt = 0; nt < 4; ++nt) bc[ss][nt] = bx[ss][nt];
        }

        #pragma unroll
        for (int nt = 0; nt < 4; ++nt) {
            float mx = 0.f;                            // relu folded into 0-init
            #pragma unroll
            for (int mt = 0; mt < 4; ++mt)
                #pragma unroll
                for (int r = 0; r < 4; ++r) mx = fmaxf(mx, acc[mt][nt][r]);
            mx = fmaxf(mx, __shfl_xor(mx, 16, 64));
            mx = fmaxf(mx, __shfl_xor(mx, 32, 64));
            if (q == 0) {
                int col = bn * 128 + n0w + nt * 16 + l15;
                atomicMax(&g[col], __float_as_int(mx));
            }
        }
    }
}

// ---------------------------------------------------------------------------
// k4: classifier head, pure f32. One wave per output row.
// ---------------------------------------------------------------------------
__global__ void k4_f1(const float* __restrict__ wf1)
{
    int r = blockIdx.x, l = threadIdx.x;
    float s = 0.f;
    #pragma unroll
    for (int i = 0; i < 16; ++i) s += wf1[r * 1024 + i * 64 + l] * g_buf[i * 64 + l];
    #pragma unroll
    for (int o = 32; o; o >>= 1) s += __shfl_down(s, o, 64);
    if (!l) f1_buf[r] = fmaxf(s, 0.f);
}
__global__ void k4_f2(const float* __restrict__ wf2)
{
    int r = blockIdx.x, l = threadIdx.x;
    float s = 0.f;
    #pragma unroll
    for (int i = 0; i < 8; ++i) s += wf2[r * 512 + i * 64 + l] * f1_buf[i * 64 + l];
    #pragma unroll
    for (int o = 32; o; o >>= 1) s += __shfl_down(s, o, 64);
    if (!l) f2_buf[r] = fmaxf(s, 0.f);
}
__global__ void k4_out(const float* __restrict__ wf3, float* __restrict__ out)
{
    int r = blockIdx.x, l = threadIdx.x;
    float s = 0.f;
    #pragma unroll
    for (int i = 0; i < 4; ++i) s += wf3[r * 256 + i * 64 + l] * f2_buf[i * 64 + l];
    #pragma unroll
    for (int o = 32; o; o >>= 1) s += __shfl_down(s, o, 64);
    if (!l) out[r] = s;
}

// ---------------------------------------------------------------------------
extern "C" void kernel_launch(void* const* d_in, const int* in_sizes, int n_in,
                              void* d_out, int out_size, void* d_ws, size_t ws_size,
                              hipStream_t stream)
{
    (void)in_sizes; (void)n_in; (void)out_size; (void)d_ws; (void)ws_size;
    const float* x   = (const float*)d_in[0];
    const int*   idx = (const int*)d_in[2];
    const float* w1  = (const float*)d_in[3];
    const float* w2  = (const float*)d_in[4];
    const float* w3  = (const float*)d_in[5];
    const float* w4  = (const float*)d_in[6];
    const float* w5  = (const float*)d_in[7];
    const float* wf1 = (const float*)d_in[8];
    const float* wf2 = (const float*)d_in[9];
    const float* wf3 = (const float*)d_in[10];

    float* gptr;
    hipGetSymbolAddress((void**)&gptr, HIP_SYMBOL(g_buf));

    k0_zero <<<1, 1024, 0, stream>>>();
    kcvt    <<<816, 256, 0, stream>>>(w3, w4, w5);
    k1_mlp  <<<262144 / 64, 256, 0, stream>>>(x, w1, w2);
    k2_pool <<<262144 / 16, 256, 0, stream>>>(idx);
    k3_fused<<<262144 / 128, 256, 0, stream>>>((int*)gptr);
    k4_f1   <<<512, 64, 0, stream>>>(wf1);
    k4_f2   <<<256, 64, 0, stream>>>(wf2);
    k4_out  <<<40, 64, 0, stream>>>(wf3, (float*)d_out);
}

// Round 9
// 459.168 us; speedup vs baseline: 1.2670x; 1.2670x over previous
//
#include <hip/hip_runtime.h>
#include <hip/hip_bf16.h>
#include <stdint.h>

typedef unsigned short u16;
typedef __bf16 bf16x8 __attribute__((ext_vector_type(8)));
typedef float  f32x4  __attribute__((ext_vector_type(4)));
typedef u16    u16x8  __attribute__((ext_vector_type(8)));

__device__ __forceinline__ float bf2f(u16 u) {
    return __uint_as_float(((unsigned)u) << 16);
}
__device__ __forceinline__ u16 f2bf(float f) {   // round-to-nearest-even
    unsigned u = __float_as_uint(f);
    u += 0x7fffu + ((u >> 16) & 1u);
    return (u16)(u >> 16);
}
__device__ __forceinline__ u16x8 maxu16(u16x8 a, u16x8 b) {
    u16x8 r;
    #pragma unroll
    for (int e = 0; e < 8; ++e) r[e] = a[e] > b[e] ? a[e] : b[e];
    return r;
}

#define MFMA16(a, b, c) __builtin_amdgcn_mfma_f32_16x16x32_bf16(a, b, c, 0, 0, 0)

// Static device buffers — no d_ws dependency.
__device__ u16   h2g_buf[262144 * 64];   // h2 [N][64] bf16 (33.5 MB)
__device__ u16   gm_buf [262144 * 64];   // neighbor-max [N][64] bf16 (33.5 MB)
__device__ u16   w3b[64 * 64];           // weights pre-converted to bf16
__device__ u16   w4b[128 * 64];
__device__ u16   w5b[1024 * 192];
__device__ float g_buf[1024];            // global column max (>= 0)
__device__ float f1_buf[512];
__device__ float f2_buf[256];

// ---------------------------------------------------------------------------
__global__ void k0_zero() { g_buf[threadIdx.x] = 0.f; }

__global__ void kcvt(const float* __restrict__ w3f, const float* __restrict__ w4f,
                     const float* __restrict__ w5f)
{
    int i = blockIdx.x * 256 + threadIdx.x;
    if (i < 4096)        w3b[i]         = f2bf(w3f[i]);
    else if (i < 12288)  w4b[i - 4096]  = f2bf(w4f[i - 4096]);
    else                 w5b[i - 12288] = f2bf(w5f[i - 12288]);
}

// ---------------------------------------------------------------------------
// k1: mlp1+mlp2 for 64 points/block (f32 in -> bf16). Writes h2g_buf.
// ---------------------------------------------------------------------------
__global__ __launch_bounds__(256) void k1_mlp(
    const float* __restrict__ xf, const float* __restrict__ w1f,
    const float* __restrict__ w2f)
{
    __shared__ __align__(16) u16 sw1[64 * 4];
    __shared__ __align__(16) u16 sx [64 * 4];
    __shared__ __align__(16) u16 sw2[64 * 72];
    __shared__ __align__(16) u16 shA[64 * 72];
    __shared__ __align__(16) u16 sh2[64 * 72];

    const int tid = threadIdx.x;
    const int p0  = blockIdx.x * 64;

    for (int i = tid; i < 64 * 64; i += 256)
        sw2[(i >> 6) * 72 + (i & 63)] = f2bf(w2f[i]);
    if (tid < 192) {
        sw1[(tid / 3) * 4 + tid % 3] = f2bf(w1f[tid]);
        sx [(tid / 3) * 4 + tid % 3] = f2bf(xf[p0 * 3 + tid]);
    }
    __syncthreads();

    {   // L1 via VALU (K=3)
        int m = tid & 63, ng = tid >> 6;
        float x0 = bf2f(sx[m * 4]), x1 = bf2f(sx[m * 4 + 1]), x2 = bf2f(sx[m * 4 + 2]);
        #pragma unroll
        for (int j = 0; j < 16; ++j) {
            int n = ng * 16 + j;
            float s = x0 * bf2f(sw1[n * 4]) + x1 * bf2f(sw1[n * 4 + 1]) + x2 * bf2f(sw1[n * 4 + 2]);
            shA[m * 72 + n] = f2bf(fmaxf(s, 0.f));
        }
    }
    __syncthreads();

    const int lane = tid & 63, w = tid >> 6, q = lane >> 4, l15 = lane & 15;
    const int mrow = 16 * w;

    f32x4 acc2[4];
    #pragma unroll
    for (int nt = 0; nt < 4; ++nt) acc2[nt] = (f32x4){0.f, 0.f, 0.f, 0.f};
    #pragma unroll
    for (int s = 0; s < 2; ++s) {
        bf16x8 a = *(const bf16x8*)&shA[(mrow + l15) * 72 + s * 32 + q * 8];
        #pragma unroll
        for (int nt = 0; nt < 4; ++nt) {
            bf16x8 b = *(const bf16x8*)&sw2[(nt * 16 + l15) * 72 + s * 32 + q * 8];
            acc2[nt] = MFMA16(a, b, acc2[nt]);
        }
    }
    #pragma unroll
    for (int nt = 0; nt < 4; ++nt)
        #pragma unroll
        for (int r = 0; r < 4; ++r) {
            int m = mrow + q * 4 + r;
            sh2[m * 72 + nt * 16 + l15] = f2bf(fmaxf(acc2[nt][r], 0.f));
        }
    __syncthreads();

    {
        int row = tid >> 2, c = (tid & 3) * 16;
        *(u16x8*)&h2g_buf[(size_t)p0 * 64 + tid * 16]     = *(const u16x8*)&sh2[row * 72 + c];
        *(u16x8*)&h2g_buf[(size_t)p0 * 64 + tid * 16 + 8] = *(const u16x8*)&sh2[row * 72 + c + 8];
    }
}

// ---------------------------------------------------------------------------
// k2_pool: 8 threads per point (thread owns a 16B channel chunk). 16
//   INDEPENDENT gather loads issued back-to-back per thread (deep MLP),
//   local packed-u16 max (valid: post-relu bf16 >= 0), direct 16B store.
//   No shuffles, no masking.
// ---------------------------------------------------------------------------
__global__ __launch_bounds__(256) void k2_pool(const int* __restrict__ idx)
{
    const size_t gt = (size_t)blockIdx.x * 256 + threadIdx.x;
    const size_t p  = gt >> 3;              // point
    const int    c  = (threadIdx.x & 7) * 8; // channel chunk

    u16x8 v[16];
    #pragma unroll
    for (int k = 0; k < 16; ++k) {
        int j = idx[p * 16 + k];
        v[k] = *(const u16x8*)&h2g_buf[(size_t)j * 64 + c];
    }
    u16x8 m = v[0];
    #pragma unroll
    for (int k = 1; k < 16; ++k) m = maxu16(m, v[k]);
    *(u16x8*)&gm_buf[p * 64 + c] = m;
}

// ---------------------------------------------------------------------------
// k3: per 128-row block, LDS = sA[128][192] (48KB) + sB0/sB1 (8KB each).
//   sA swizzle: (r,k) -> r*192 + P*8 + (k&7), P=(j&24)|((j^r)&7), j=k>>3.
//   sB swizzle: (r,k) -> r*64 + ((j^r)&7)*8 + (k&7).
//     stage gm -> sA cols 0..63, h2 -> cols 64..127
//     P4 h3 = relu(h2@w3^T) -> cols 128..191  (wave-local rows, no barrier)
//     P5 h4 = relu(h3@w4^T) -> cols 64..191   (safe via within-wave deps)
//   All 24 A-frags cached in VGPRs (sA read exactly once).  mlp5 B staged
//   cooperatively through double-buffered LDS (16KB/stage, 1 barrier/stage);
//   LDS per CU-stage = 96KB -> ~1130cyc vs 310cyc matrix -> ~27% MfmaUtil.
// ---------------------------------------------------------------------------
__global__ __launch_bounds__(256) void k3_fused(int* __restrict__ g)
{
    __shared__ __align__(16) u16 lds[128 * 192 + 2 * 128 * 64];  // 64 KB
    u16* sA  = lds;
    u16* sB0 = lds + 24576;
    u16* sB1 = lds + 24576 + 8192;

    const int tid  = threadIdx.x;
    const size_t R0 = (size_t)blockIdx.x * 128;
    const int lane = tid & 63, w = tid >> 6, q = lane >> 4, l15 = lane & 15;
    const int m0w  = (w & 1) * 64, n0w = (w >> 1) * 64;

    // ---- stage gm -> cols 0..63 (j=0..7), h2 -> cols 64..127 (j=8..15) ----
    #pragma unroll
    for (int c = 0; c < 4; ++c) {
        int i = c * 256 + tid, r = i >> 3, js = i & 7;
        *(u16x8*)&sA[r * 192 + ((js ^ r) & 7) * 8] =
            *(const u16x8*)&gm_buf[(R0 + r) * 64 + js * 8];
        *(u16x8*)&sA[r * 192 + (8 | ((js ^ r) & 7)) * 8] =
            *(const u16x8*)&h2g_buf[(R0 + r) * 64 + js * 8];
    }
    __syncthreads();

    // ---- P4: h3 = relu(h2 @ w3^T) -> cols 128..191 (wave-local rows) ----
    {
        f32x4 a3[2][4];
        #pragma unroll
        for (int mt = 0; mt < 2; ++mt)
            #pragma unroll
            for (int nt = 0; nt < 4; ++nt) a3[mt][nt] = (f32x4){0.f, 0.f, 0.f, 0.f};
        #pragma unroll
        for (int ss = 0; ss < 2; ++ss) {
            int js = ss * 4 + q;
            bf16x8 a[2], b[4];
            #pragma unroll
            for (int mt = 0; mt < 2; ++mt) {
                int r = w * 32 + mt * 16 + l15;
                a[mt] = *(const bf16x8*)&sA[r * 192 + (8 | ((js ^ r) & 7)) * 8];
            }
            #pragma unroll
            for (int nt = 0; nt < 4; ++nt)
                b[nt] = *(const bf16x8*)&w3b[(nt * 16 + l15) * 64 + ss * 32 + q * 8];
            #pragma unroll
            for (int mt = 0; mt < 2; ++mt)
                #pragma unroll
                for (int nt = 0; nt < 4; ++nt)
                    a3[mt][nt] = MFMA16(a[mt], b[nt], a3[mt][nt]);
        }
        #pragma unroll
        for (int mt = 0; mt < 2; ++mt)
            #pragma unroll
            for (int nt = 0; nt < 4; ++nt)
                #pragma unroll
                for (int r = 0; r < 4; ++r) {
                    int m = w * 32 + mt * 16 + q * 4 + r;
                    int n = nt * 16 + l15;
                    sA[m * 192 + (16 | (((n >> 3) ^ m) & 7)) * 8 + (n & 7)] =
                        f2bf(fmaxf(a3[mt][nt][r], 0.f));
                }
    }
    // no barrier: P4 writes and P5 reads are wave-local rows

    // ---- P5: h4 = relu(h3 @ w4^T) -> cols 64..191 ----
    {
        f32x4 a4[2][8];
        #pragma unroll
        for (int mt = 0; mt < 2; ++mt)
            #pragma unroll
            for (int nt = 0; nt < 8; ++nt) a4[mt][nt] = (f32x4){0.f, 0.f, 0.f, 0.f};
        #pragma unroll
        for (int ss = 0; ss < 2; ++ss) {
            int js = ss * 4 + q;
            bf16x8 a[2];
            #pragma unroll
            for (int mt = 0; mt < 2; ++mt) {
                int r = w * 32 + mt * 16 + l15;
                a[mt] = *(const bf16x8*)&sA[r * 192 + (16 | ((js ^ r) & 7)) * 8];
            }
            #pragma unroll
            for (int nt = 0; nt < 8; ++nt) {
                bf16x8 b = *(const bf16x8*)&w4b[(nt * 16 + l15) * 64 + ss * 32 + q * 8];
                #pragma unroll
                for (int mt = 0; mt < 2; ++mt)
                    a4[mt][nt] = MFMA16(a[mt], b, a4[mt][nt]);
            }
        }
        #pragma unroll
        for (int mt = 0; mt < 2; ++mt)
            #pragma unroll
            for (int nt = 0; nt < 8; ++nt)
                #pragma unroll
                for (int r = 0; r < 4; ++r) {
                    int m  = w * 32 + mt * 16 + q * 4 + r;
                    int n4 = nt * 16 + l15;
                    int j  = 8 + (n4 >> 3);
                    int p  = (j & 24) | ((j ^ m) & 7);
                    sA[m * 192 + p * 8 + (n4 & 7)] = f2bf(fmaxf(a4[mt][nt][r], 0.f));
                }
    }
    __syncthreads();

    // ---- cache all 24 A-frags in VGPRs (sA read exactly once) ----
    bf16x8 areg[3][2][4];                 // [kt][ss][mt]
    #pragma unroll
    for (int kt = 0; kt < 3; ++kt)
        #pragma unroll
        for (int ss = 0; ss < 2; ++ss) {
            int js = ss * 4 + q;
            #pragma unroll
            for (int mt = 0; mt < 4; ++mt) {
                int r = m0w + mt * 16 + l15;
                int p = (kt * 8) | ((js ^ r) & 7);
                areg[kt][ss][mt] = *(const bf16x8*)&sA[r * 192 + p * 8];
            }
        }

    // ---- mlp5: B double-buffered through LDS, 1 barrier/stage ----
    u16x8 v[4];
    #pragma unroll
    for (int c = 0; c < 4; ++c) {         // preload stage 0 (bn=0,kt=0)
        int i = c * 256 + tid, r = i >> 3, js = i & 7;
        v[c] = *(const u16x8*)&w5b[(size_t)r * 192 + js * 8];
    }
    #pragma unroll
    for (int c = 0; c < 4; ++c) {
        int i = c * 256 + tid, r = i >> 3, js = i & 7;
        *(u16x8*)&sB0[r * 64 + ((js ^ r) & 7) * 8] = v[c];
    }

    int s = 0;
    for (int bn = 0; bn < 8; ++bn) {
        f32x4 acc[4][4];
        #pragma unroll
        for (int mt = 0; mt < 4; ++mt)
            #pragma unroll
            for (int nt = 0; nt < 4; ++nt) acc[mt][nt] = (f32x4){0.f, 0.f, 0.f, 0.f};

        #pragma unroll
        for (int kt = 0; kt < 3; ++kt, ++s) {
            if (s < 23) {                  // prefetch stage s+1 into VGPRs
                int s1 = s + 1, bn1 = s1 / 3, kt1 = s1 - bn1 * 3;
                #pragma unroll
                for (int c = 0; c < 4; ++c) {
                    int i = c * 256 + tid, r = i >> 3, js = i & 7;
                    v[c] = *(const u16x8*)&w5b[(size_t)(bn1 * 128 + r) * 192 + kt1 * 64 + js * 8];
                }
            }
            __syncthreads();               // cur buffer visible; prev reads done
            const u16* sBc = (s & 1) ? sB1 : sB0;
            bf16x8 b[2][4];
            #pragma unroll
            for (int ss = 0; ss < 2; ++ss) {
                int js = ss * 4 + q;
                #pragma unroll
                for (int nt = 0; nt < 4; ++nt) {
                    int r = n0w + nt * 16 + l15;
                    b[ss][nt] = *(const bf16x8*)&sBc[r * 64 + ((js ^ r) & 7) * 8];
                }
            }
            #pragma unroll
            for (int ss = 0; ss < 2; ++ss)
                #pragma unroll
                for (int mt = 0; mt < 4; ++mt)
                    #pragma unroll
                    for (int nt = 0; nt < 4; ++nt)
                        acc[mt][nt] = MFMA16(areg[kt][ss][mt], b[ss][nt], acc[mt][nt]);
            if (s < 23) {                  // write prefetched stage to other buffer
                u16* sBn = (s & 1) ? sB0 : sB1;
                #pragma unroll
                for (int c = 0; c < 4; ++c) {
                    int i = c * 256 + tid, r = i >> 3, js = i & 7;
                    *(u16x8*)&sBn[r * 64 + ((js ^ r) & 7) * 8] = v[c];
                }
            }
        }

        #pragma unroll
        for (int nt = 0; nt < 4; ++nt) {
            float mx = 0.f;                            // relu folded into 0-init
            #pragma unroll
            for (int mt = 0; mt < 4; ++mt)
                #pragma unroll
                for (int r = 0; r < 4; ++r) mx = fmaxf(mx, acc[mt][nt][r]);
            mx = fmaxf(mx, __shfl_xor(mx, 16, 64));
            mx = fmaxf(mx, __shfl_xor(mx, 32, 64));
            if (q == 0) {
                int col = bn * 128 + n0w + nt * 16 + l15;
                atomicMax(&g[col], __float_as_int(mx));
            }
        }
    }
}

// ---------------------------------------------------------------------------
// k4: classifier head, pure f32. One wave per output row.
// ---------------------------------------------------------------------------
__global__ void k4_f1(const float* __restrict__ wf1)
{
    int r = blockIdx.x, l = threadIdx.x;
    float s = 0.f;
    #pragma unroll
    for (int i = 0; i < 16; ++i) s += wf1[r * 1024 + i * 64 + l] * g_buf[i * 64 + l];
    #pragma unroll
    for (int o = 32; o; o >>= 1) s += __shfl_down(s, o, 64);
    if (!l) f1_buf[r] = fmaxf(s, 0.f);
}
__global__ void k4_f2(const float* __restrict__ wf2)
{
    int r = blockIdx.x, l = threadIdx.x;
    float s = 0.f;
    #pragma unroll
    for (int i = 0; i < 8; ++i) s += wf2[r * 512 + i * 64 + l] * f1_buf[i * 64 + l];
    #pragma unroll
    for (int o = 32; o; o >>= 1) s += __shfl_down(s, o, 64);
    if (!l) f2_buf[r] = fmaxf(s, 0.f);
}
__global__ void k4_out(const float* __restrict__ wf3, float* __restrict__ out)
{
    int r = blockIdx.x, l = threadIdx.x;
    float s = 0.f;
    #pragma unroll
    for (int i = 0; i < 4; ++i) s += wf3[r * 256 + i * 64 + l] * f2_buf[i * 64 + l];
    #pragma unroll
    for (int o = 32; o; o >>= 1) s += __shfl_down(s, o, 64);
    if (!l) out[r] = s;
}

// ---------------------------------------------------------------------------
extern "C" void kernel_launch(void* const* d_in, const int* in_sizes, int n_in,
                              void* d_out, int out_size, void* d_ws, size_t ws_size,
                              hipStream_t stream)
{
    (void)in_sizes; (void)n_in; (void)out_size; (void)d_ws; (void)ws_size;
    const float* x   = (const float*)d_in[0];
    const int*   idx = (const int*)d_in[2];
    const float* w1  = (const float*)d_in[3];
    const float* w2  = (const float*)d_in[4];
    const float* w3  = (const float*)d_in[5];
    const float* w4  = (const float*)d_in[6];
    const float* w5  = (const float*)d_in[7];
    const float* wf1 = (const float*)d_in[8];
    const float* wf2 = (const float*)d_in[9];
    const float* wf3 = (const float*)d_in[10];

    float* gptr;
    hipGetSymbolAddress((void**)&gptr, HIP_SYMBOL(g_buf));

    k0_zero <<<1, 1024, 0, stream>>>();
    kcvt    <<<816, 256, 0, stream>>>(w3, w4, w5);
    k1_mlp  <<<262144 / 64, 256, 0, stream>>>(x, w1, w2);
    k2_pool <<<262144 * 8 / 256, 256, 0, stream>>>(idx);
    k3_fused<<<262144 / 128, 256, 0, stream>>>((int*)gptr);
    k4_f1   <<<512, 64, 0, stream>>>(wf1);
    k4_f2   <<<256, 64, 0, stream>>>(wf2);
    k4_out  <<<40, 64, 0, stream>>>(wf3, (float*)d_out);
}